// Round 1
// baseline (545.257 us; speedup 1.0000x reference)
//
#include <hip/hip_runtime.h>

typedef __attribute__((ext_vector_type(4))) float  float4_;
typedef __attribute__((ext_vector_type(8))) short  short8;
typedef __attribute__((ext_vector_type(8))) __bf16 bf16x8;

__device__ inline unsigned short f2bf(float f) {
    unsigned u = __builtin_bit_cast(unsigned, f);
    u += 0x7FFFu + ((u >> 16) & 1u);          // round-to-nearest-even
    return (unsigned short)(u >> 16);
}

__device__ inline bf16x8 zero8() {
    short8 z = {0, 0, 0, 0, 0, 0, 0, 0};
    return __builtin_bit_cast(bf16x8, z);
}

__device__ inline float4_ mfma16(bf16x8 a, bf16x8 b, float4_ c) {
    return __builtin_amdgcn_mfma_f32_16x16x32_bf16(a, b, c, 0, 0, 0);
}

// ---------------- weight packing into B-fragment order ----------------
// frag f = (k*ctn + ct)*ntn + nt ; within frag: elem = lane*8 + t
// value = W[k][ct*32 + (lane>>4)*8 + t][nt*16 + (lane&15)]

__global__ void packW_kernel(const float* __restrict__ src, unsigned short* __restrict__ dst,
                             int cin, int cout, int total) {
    int e = blockIdx.x * 256 + threadIdx.x;
    if (e >= total) return;
    int f = e >> 9, i = e & 511, lane = i >> 3, t = i & 7;
    int ntn = cout >> 4, ctn = cin >> 5;
    int nt = f % ntn;
    int rest = f / ntn;
    int ct = rest % ctn;
    int k = rest / ctn;
    int c = ct * 32 + (lane >> 4) * 8 + t;
    int j = nt * 16 + (lane & 15);
    dst[e] = f2bf(src[(k * cin + c) * cout + j]);
}

// W1|W2 side by side -> (64, 128)
__global__ void pack2_kernel(const float* __restrict__ W1, const float* __restrict__ W2,
                             unsigned short* __restrict__ dst) {
    int e = blockIdx.x * 256 + threadIdx.x;   // 16 frags * 512 = 8192
    if (e >= 8192) return;
    int f = e >> 9, i = e & 511, lane = i >> 3, t = i & 7;
    int nt = f & 7, ct = f >> 3;
    int c = ct * 32 + (lane >> 4) * 8 + t;
    int j = nt * 16 + (lane & 15);
    float v = (j < 64) ? W1[c * 64 + j] : W2[c * 64 + (j - 64)];
    dst[e] = f2bf(v);
}

// ---------------- blk1 dual: f1|f2 = relu(LN(x@W + b)) ----------------
// wave handles 16 rows x 128 cols; K=64 (2 ktiles); 8 ntiles
__global__ __launch_bounds__(256) void blk12_kernel(
    const float* __restrict__ x, unsigned short* cat,
    const unsigned short* __restrict__ Wp,
    const float* __restrict__ b1, const float* __restrict__ g1, const float* __restrict__ be1,
    const float* __restrict__ b2, const float* __restrict__ g2, const float* __restrict__ be2) {
    int tid = threadIdx.x, lane = tid & 63, wv = tid >> 6;
    int l15 = lane & 15, q = lane >> 4;
    long base = ((long)blockIdx.x * 4 + wv) * 16;

    float4_ acc[8];
#pragma unroll
    for (int i = 0; i < 8; i++) acc[i] = (float4_){0.f, 0.f, 0.f, 0.f};

#pragma unroll
    for (int kt = 0; kt < 2; kt++) {
        const float* xp = x + (base + l15) * 64 + kt * 32 + q * 8;
        float4_ f0 = *(const float4_*)xp;
        float4_ f1 = *(const float4_*)(xp + 4);
        short8 as;
        as[0] = (short)f2bf(f0[0]); as[1] = (short)f2bf(f0[1]);
        as[2] = (short)f2bf(f0[2]); as[3] = (short)f2bf(f0[3]);
        as[4] = (short)f2bf(f1[0]); as[5] = (short)f2bf(f1[1]);
        as[6] = (short)f2bf(f1[2]); as[7] = (short)f2bf(f1[3]);
        bf16x8 a = __builtin_bit_cast(bf16x8, as);
        const unsigned short* wp = Wp + (size_t)kt * 8 * 512;
#pragma unroll
        for (int nt = 0; nt < 8; nt++) {
            bf16x8 w = *(const bf16x8*)(wp + nt * 512 + lane * 8);
            acc[nt] = mfma16(a, w, acc[nt]);
        }
    }

    float bc[8], gc[8], bec[8];
#pragma unroll
    for (int nt = 0; nt < 8; nt++) {
        int j = nt * 16 + l15;
        if (j < 64) { bc[nt] = b1[j]; gc[nt] = g1[j]; bec[nt] = be1[j]; }
        else        { bc[nt] = b2[j - 64]; gc[nt] = g2[j - 64]; bec[nt] = be2[j - 64]; }
    }

#pragma unroll
    for (int r = 0; r < 4; r++) {
        long row = base + q * 4 + r;
        float v[8], s0 = 0.f, s1 = 0.f, q0 = 0.f, q1 = 0.f;
#pragma unroll
        for (int nt = 0; nt < 4; nt++) { v[nt] = acc[nt][r] + bc[nt]; s0 += v[nt]; q0 += v[nt] * v[nt]; }
#pragma unroll
        for (int nt = 4; nt < 8; nt++) { v[nt] = acc[nt][r] + bc[nt]; s1 += v[nt]; q1 += v[nt] * v[nt]; }
#pragma unroll
        for (int m = 1; m < 16; m <<= 1) {
            s0 += __shfl_xor(s0, m); q0 += __shfl_xor(q0, m);
            s1 += __shfl_xor(s1, m); q1 += __shfl_xor(q1, m);
        }
        float mu0 = s0 * (1.f / 64), var0 = q0 * (1.f / 64) - mu0 * mu0, inv0 = rsqrtf(var0 + 1e-5f);
        float mu1 = s1 * (1.f / 64), var1 = q1 * (1.f / 64) - mu1 * mu1, inv1 = rsqrtf(var1 + 1e-5f);
        unsigned short* cp = cat + row * 256;
#pragma unroll
        for (int nt = 0; nt < 4; nt++) {
            float y = fmaxf((v[nt] - mu0) * inv0 * gc[nt] + bec[nt], 0.f);
            cp[nt * 16 + l15] = f2bf(y);
        }
#pragma unroll
        for (int nt = 4; nt < 8; nt++) {
            float y = fmaxf((v[nt] - mu1) * inv1 * gc[nt] + bec[nt], 0.f);
            cp[nt * 16 + l15] = f2bf(y);
        }
    }
}

// ---------------- submanifold conv blk3: relu(LN(sum_k gather_k(x)@Wk + b)) ----------
// wave: 32 rows (2 mtiles) x 32 cols (2 ntiles); CT = cin/32
template <int CT>
__global__ __launch_bounds__(256) void conv_kernel(
    unsigned short* cat, const int* __restrict__ nbr,
    const unsigned short* __restrict__ Wp,
    const float* __restrict__ bb, const float* __restrict__ gg, const float* __restrict__ bee,
    int in_off, int out_off) {
    int tid = threadIdx.x, lane = tid & 63, wv = tid >> 6;
    int l15 = lane & 15, q = lane >> 4;
    long base = ((long)blockIdx.x * 4 + wv) * 32;

    float4_ acc[2][2];
#pragma unroll
    for (int a = 0; a < 2; a++)
#pragma unroll
        for (int bn = 0; bn < 2; bn++) acc[a][bn] = (float4_){0.f, 0.f, 0.f, 0.f};

    const int* nb0p = nbr + (base + l15) * 27;
    const int* nb1p = nbr + (base + 16 + l15) * 27;

    for (int k = 0; k < 27; k++) {
        int nb0 = nb0p[k];
        int nb1 = nb1p[k];
#pragma unroll
        for (int ct = 0; ct < CT; ct++) {
            bf16x8 a0 = zero8(), a1 = zero8();
            if (nb0 >= 0) a0 = *(const bf16x8*)(cat + (size_t)nb0 * 256 + in_off + ct * 32 + q * 8);
            if (nb1 >= 0) a1 = *(const bf16x8*)(cat + (size_t)nb1 * 256 + in_off + ct * 32 + q * 8);
            const unsigned short* wp = Wp + ((size_t)(k * CT + ct) * 2) * 512;
            bf16x8 w0 = *(const bf16x8*)(wp + lane * 8);
            bf16x8 w1 = *(const bf16x8*)(wp + 512 + lane * 8);
            acc[0][0] = mfma16(a0, w0, acc[0][0]);
            acc[0][1] = mfma16(a0, w1, acc[0][1]);
            acc[1][0] = mfma16(a1, w0, acc[1][0]);
            acc[1][1] = mfma16(a1, w1, acc[1][1]);
        }
    }

    float b0c = bb[l15], b1c = bb[16 + l15];
    float g0c = gg[l15], g1c = gg[16 + l15];
    float be0c = bee[l15], be1c = bee[16 + l15];

#pragma unroll
    for (int mt = 0; mt < 2; mt++) {
#pragma unroll
        for (int r = 0; r < 4; r++) {
            long row = base + mt * 16 + q * 4 + r;
            float v0 = acc[mt][0][r] + b0c;
            float v1 = acc[mt][1][r] + b1c;
            float s = v0 + v1, sq = v0 * v0 + v1 * v1;
#pragma unroll
            for (int m = 1; m < 16; m <<= 1) { s += __shfl_xor(s, m); sq += __shfl_xor(sq, m); }
            float mu = s * (1.f / 32), var = sq * (1.f / 32) - mu * mu, inv = rsqrtf(var + 1e-5f);
            float y0 = fmaxf((v0 - mu) * inv * g0c + be0c, 0.f);
            float y1 = fmaxf((v1 - mu) * inv * g1c + be1c, 0.f);
            unsigned short* cp = cat + row * 256 + out_off;
            cp[l15] = f2bf(y0);
            cp[16 + l15] = f2bf(y1);
        }
    }
}

// ---------------- final blk1: out = relu(LN(cat@W7 + b7)) ----------------
__global__ __launch_bounds__(256) void blk7_kernel(
    const unsigned short* __restrict__ cat, const unsigned short* __restrict__ Wp,
    const float* __restrict__ b, const float* __restrict__ g, const float* __restrict__ be,
    float* __restrict__ out) {
    int tid = threadIdx.x, lane = tid & 63, wv = tid >> 6;
    int l15 = lane & 15, q = lane >> 4;
    long base = ((long)blockIdx.x * 4 + wv) * 16;

    float4_ acc[4];
#pragma unroll
    for (int i = 0; i < 4; i++) acc[i] = (float4_){0.f, 0.f, 0.f, 0.f};

#pragma unroll
    for (int kt = 0; kt < 8; kt++) {
        bf16x8 a = *(const bf16x8*)(cat + (base + l15) * 256 + kt * 32 + q * 8);
        const unsigned short* wp = Wp + (size_t)kt * 4 * 512;
#pragma unroll
        for (int nt = 0; nt < 4; nt++) {
            bf16x8 w = *(const bf16x8*)(wp + nt * 512 + lane * 8);
            acc[nt] = mfma16(a, w, acc[nt]);
        }
    }

    float bc[4], gc[4], bec[4];
#pragma unroll
    for (int nt = 0; nt < 4; nt++) {
        int j = nt * 16 + l15;
        bc[nt] = b[j]; gc[nt] = g[j]; bec[nt] = be[j];
    }

#pragma unroll
    for (int r = 0; r < 4; r++) {
        long row = base + q * 4 + r;
        float v[4], s = 0.f, sq = 0.f;
#pragma unroll
        for (int nt = 0; nt < 4; nt++) { v[nt] = acc[nt][r] + bc[nt]; s += v[nt]; sq += v[nt] * v[nt]; }
#pragma unroll
        for (int m = 1; m < 16; m <<= 1) { s += __shfl_xor(s, m); sq += __shfl_xor(sq, m); }
        float mu = s * (1.f / 64), var = sq * (1.f / 64) - mu * mu, inv = rsqrtf(var + 1e-5f);
#pragma unroll
        for (int nt = 0; nt < 4; nt++) {
            float y = fmaxf((v[nt] - mu) * inv * gc[nt] + bec[nt], 0.f);
            out[row * 64 + nt * 16 + l15] = y;
        }
    }
}

extern "C" void kernel_launch(void* const* d_in, const int* in_sizes, int n_in,
                              void* d_out, int out_size, void* d_ws, size_t ws_size,
                              hipStream_t stream) {
    const int N = in_sizes[0] / 64;   // 262144

    const float* x   = (const float*)d_in[0];
    const int*   nbr = (const int*)d_in[1];
    const float* W1 = (const float*)d_in[2];
    const float* b1 = (const float*)d_in[3];
    const float* g1 = (const float*)d_in[4];
    const float* be1 = (const float*)d_in[5];
    const float* W2 = (const float*)d_in[6];
    const float* b2 = (const float*)d_in[7];
    const float* g2 = (const float*)d_in[8];
    const float* be2 = (const float*)d_in[9];
    const float* W3 = (const float*)d_in[10];
    const float* b3 = (const float*)d_in[11];
    const float* g3 = (const float*)d_in[12];
    const float* be3 = (const float*)d_in[13];
    const float* W4 = (const float*)d_in[14];
    const float* b4 = (const float*)d_in[15];
    const float* g4 = (const float*)d_in[16];
    const float* be4 = (const float*)d_in[17];
    const float* W5 = (const float*)d_in[18];
    const float* b5 = (const float*)d_in[19];
    const float* g5 = (const float*)d_in[20];
    const float* be5 = (const float*)d_in[21];
    const float* W6 = (const float*)d_in[22];
    const float* b6 = (const float*)d_in[23];
    const float* g6 = (const float*)d_in[24];
    const float* be6 = (const float*)d_in[25];
    const float* W7 = (const float*)d_in[26];
    const float* b7 = (const float*)d_in[27];
    const float* g7 = (const float*)d_in[28];
    const float* be7 = (const float*)d_in[29];

    unsigned short* ws   = (unsigned short*)d_ws;
    unsigned short* cat  = ws;                               // N*256 bf16
    unsigned short* Wp12 = cat + (size_t)N * 256;            // 8192
    unsigned short* Wp3  = Wp12 + 8192;                      // 27*2*2*512 = 55296
    unsigned short* Wp4  = Wp3 + 55296;                      // 27*1*2*512 = 27648
    unsigned short* Wp5  = Wp4 + 27648;
    unsigned short* Wp6  = Wp5 + 27648;
    unsigned short* Wp7  = Wp6 + 27648;                      // 8*4*512 = 16384

    pack2_kernel<<<32, 256, 0, stream>>>(W1, W2, Wp12);
    packW_kernel<<<(55296 + 255) / 256, 256, 0, stream>>>(W3, Wp3, 64, 32, 55296);
    packW_kernel<<<(27648 + 255) / 256, 256, 0, stream>>>(W4, Wp4, 32, 32, 27648);
    packW_kernel<<<(27648 + 255) / 256, 256, 0, stream>>>(W5, Wp5, 32, 32, 27648);
    packW_kernel<<<(27648 + 255) / 256, 256, 0, stream>>>(W6, Wp6, 32, 32, 27648);
    packW_kernel<<<(16384 + 255) / 256, 256, 0, stream>>>(W7, Wp7, 256, 64, 16384);

    blk12_kernel<<<N / 64, 256, 0, stream>>>(x, cat, Wp12, b1, g1, be1, b2, g2, be2);
    conv_kernel<2><<<N / 128, 256, 0, stream>>>(cat, nbr, Wp3, b3, g3, be3, 64, 128);
    conv_kernel<1><<<N / 128, 256, 0, stream>>>(cat, nbr, Wp4, b4, g4, be4, 128, 160);
    conv_kernel<1><<<N / 128, 256, 0, stream>>>(cat, nbr, Wp5, b5, g5, be5, 160, 192);
    conv_kernel<1><<<N / 128, 256, 0, stream>>>(cat, nbr, Wp6, b6, g6, be6, 192, 224);
    blk7_kernel<<<N / 64, 256, 0, stream>>>(cat, Wp7, b7, g7, be7, (float*)d_out);
}

// Round 2
// 509.549 us; speedup vs baseline: 1.0701x; 1.0701x over previous
//
#include <hip/hip_runtime.h>

typedef __attribute__((ext_vector_type(4))) float  float4_;
typedef __attribute__((ext_vector_type(8))) short  short8;
typedef __attribute__((ext_vector_type(8))) __bf16 bf16x8;

__device__ inline unsigned short f2bf(float f) {
    unsigned u = __builtin_bit_cast(unsigned, f);
    u += 0x7FFFu + ((u >> 16) & 1u);          // round-to-nearest-even
    return (unsigned short)(u >> 16);
}

__device__ inline float4_ mfma16(bf16x8 a, bf16x8 b, float4_ c) {
    return __builtin_amdgcn_mfma_f32_16x16x32_bf16(a, b, c, 0, 0, 0);
}

// ---------------- weight packing into B-fragment order ----------------
// frag f = (k*ctn + ct)*ntn + nt ; within frag: elem = lane*8 + t
// value = W[k][ct*32 + (lane>>4)*8 + t][nt*16 + (lane&15)]

__global__ void packW_kernel(const float* __restrict__ src, unsigned short* __restrict__ dst,
                             int cin, int cout, int total) {
    int e = blockIdx.x * 256 + threadIdx.x;
    if (e >= total) return;
    int f = e >> 9, i = e & 511, lane = i >> 3, t = i & 7;
    int ntn = cout >> 4, ctn = cin >> 5;
    int nt = f % ntn;
    int rest = f / ntn;
    int ct = rest % ctn;
    int k = rest / ctn;
    int c = ct * 32 + (lane >> 4) * 8 + t;
    int j = nt * 16 + (lane & 15);
    dst[e] = f2bf(src[(k * cin + c) * cout + j]);
}

// W1|W2 side by side -> (64, 128)
__global__ void pack2_kernel(const float* __restrict__ W1, const float* __restrict__ W2,
                             unsigned short* __restrict__ dst) {
    int e = blockIdx.x * 256 + threadIdx.x;   // 16 frags * 512 = 8192
    if (e >= 8192) return;
    int f = e >> 9, i = e & 511, lane = i >> 3, t = i & 7;
    int nt = f & 7, ct = f >> 3;
    int c = ct * 32 + (lane >> 4) * 8 + t;
    int j = nt * 16 + (lane & 15);
    float v = (j < 64) ? W1[c * 64 + j] : W2[c * 64 + (j - 64)];
    dst[e] = f2bf(v);
}

// zero the sentinel row cat[N] (gather target for invalid neighbors)
__global__ void zero_row_kernel(unsigned short* cat, int N) {
    ((unsigned*)(cat + (size_t)N * 256))[threadIdx.x] = 0;   // 128 threads x 4B
}

// ---------------- blk1 dual: f1|f2 = relu(LN(x@W + b)) ----------------
__global__ __launch_bounds__(256) void blk12_kernel(
    const float* __restrict__ x, unsigned short* cat,
    const unsigned short* __restrict__ Wp,
    const float* __restrict__ b1, const float* __restrict__ g1, const float* __restrict__ be1,
    const float* __restrict__ b2, const float* __restrict__ g2, const float* __restrict__ be2) {
    int tid = threadIdx.x, lane = tid & 63, wv = tid >> 6;
    int l15 = lane & 15, q = lane >> 4;
    long base = ((long)blockIdx.x * 4 + wv) * 16;

    float4_ acc[8];
#pragma unroll
    for (int i = 0; i < 8; i++) acc[i] = (float4_){0.f, 0.f, 0.f, 0.f};

#pragma unroll
    for (int kt = 0; kt < 2; kt++) {
        const float* xp = x + (base + l15) * 64 + kt * 32 + q * 8;
        float4_ f0 = *(const float4_*)xp;
        float4_ f1 = *(const float4_*)(xp + 4);
        short8 as;
        as[0] = (short)f2bf(f0[0]); as[1] = (short)f2bf(f0[1]);
        as[2] = (short)f2bf(f0[2]); as[3] = (short)f2bf(f0[3]);
        as[4] = (short)f2bf(f1[0]); as[5] = (short)f2bf(f1[1]);
        as[6] = (short)f2bf(f1[2]); as[7] = (short)f2bf(f1[3]);
        bf16x8 a = __builtin_bit_cast(bf16x8, as);
        const unsigned short* wp = Wp + (size_t)kt * 8 * 512;
#pragma unroll
        for (int nt = 0; nt < 8; nt++) {
            bf16x8 w = *(const bf16x8*)(wp + nt * 512 + lane * 8);
            acc[nt] = mfma16(a, w, acc[nt]);
        }
    }

    float bc[8], gc[8], bec[8];
#pragma unroll
    for (int nt = 0; nt < 8; nt++) {
        int j = nt * 16 + l15;
        if (j < 64) { bc[nt] = b1[j]; gc[nt] = g1[j]; bec[nt] = be1[j]; }
        else        { bc[nt] = b2[j - 64]; gc[nt] = g2[j - 64]; bec[nt] = be2[j - 64]; }
    }

#pragma unroll
    for (int r = 0; r < 4; r++) {
        long row = base + q * 4 + r;
        float v[8], s0 = 0.f, s1 = 0.f, q0 = 0.f, q1 = 0.f;
#pragma unroll
        for (int nt = 0; nt < 4; nt++) { v[nt] = acc[nt][r] + bc[nt]; s0 += v[nt]; q0 += v[nt] * v[nt]; }
#pragma unroll
        for (int nt = 4; nt < 8; nt++) { v[nt] = acc[nt][r] + bc[nt]; s1 += v[nt]; q1 += v[nt] * v[nt]; }
#pragma unroll
        for (int m = 1; m < 16; m <<= 1) {
            s0 += __shfl_xor(s0, m); q0 += __shfl_xor(q0, m);
            s1 += __shfl_xor(s1, m); q1 += __shfl_xor(q1, m);
        }
        float mu0 = s0 * (1.f / 64), var0 = q0 * (1.f / 64) - mu0 * mu0, inv0 = rsqrtf(var0 + 1e-5f);
        float mu1 = s1 * (1.f / 64), var1 = q1 * (1.f / 64) - mu1 * mu1, inv1 = rsqrtf(var1 + 1e-5f);
        unsigned short* cp = cat + row * 256;
#pragma unroll
        for (int nt = 0; nt < 4; nt++) {
            float y = fmaxf((v[nt] - mu0) * inv0 * gc[nt] + bec[nt], 0.f);
            cp[nt * 16 + l15] = f2bf(y);
        }
#pragma unroll
        for (int nt = 4; nt < 8; nt++) {
            float y = fmaxf((v[nt] - mu1) * inv1 * gc[nt] + bec[nt], 0.f);
            cp[nt * 16 + l15] = f2bf(y);
        }
    }
}

// ---------------- submanifold conv blk3 ----------------
// Software-pipelined: gather k+1 and idx k+2 issue while MFMA-ing tile k.
// Invalid neighbors -> sentinel zero row cat[N] (branch-free cndmask).
// MT m-tiles (MT*16 rows/wave), 2 n-tiles (32 out ch), CT = cin/32.
template <int CT, int MT>
__global__ __launch_bounds__(256) void conv_kernel(
    unsigned short* cat, const int* __restrict__ nbr,
    const unsigned short* __restrict__ Wp,
    const float* __restrict__ bb, const float* __restrict__ gg, const float* __restrict__ bee,
    int in_off, int out_off, int N) {
    int tid = threadIdx.x, lane = tid & 63, wv = tid >> 6;
    int l15 = lane & 15, q = lane >> 4;
    long base = ((long)blockIdx.x * 4 + wv) * (MT * 16);

    float4_ acc[MT][2];
#pragma unroll
    for (int mt = 0; mt < MT; mt++) {
        acc[mt][0] = (float4_){0.f, 0.f, 0.f, 0.f};
        acc[mt][1] = (float4_){0.f, 0.f, 0.f, 0.f};
    }

    const unsigned short* catp = cat + in_off + q * 8;
    const int* nbp[MT];
#pragma unroll
    for (int mt = 0; mt < MT; mt++) nbp[mt] = nbr + (base + mt * 16 + l15) * 27;

    int idxn[MT];
    bf16x8 a[MT][CT], b[MT][CT];
    // prologue: idx(0) -> gather(0) into a ; idx(1) staged in idxn
#pragma unroll
    for (int mt = 0; mt < MT; mt++) {
        int v = nbp[mt][0];
        int ic = v < 0 ? N : v;
#pragma unroll
        for (int ct = 0; ct < CT; ct++)
            a[mt][ct] = *(const bf16x8*)(catp + (size_t)ic * 256 + ct * 32);
    }
#pragma unroll
    for (int mt = 0; mt < MT; mt++) {
        int v = nbp[mt][1];
        idxn[mt] = v < 0 ? N : v;
    }

    const unsigned short* wp = Wp + lane * 8;
    for (int k = 0; k < 27; k++) {
        int k2 = (k + 2 < 27) ? k + 2 : 26;
        int idx2[MT];
#pragma unroll
        for (int mt = 0; mt < MT; mt++) {
            int v = nbp[mt][k2];
            idx2[mt] = v < 0 ? N : v;
        }
#pragma unroll
        for (int mt = 0; mt < MT; mt++)
#pragma unroll
            for (int ct = 0; ct < CT; ct++)
                b[mt][ct] = *(const bf16x8*)(catp + (size_t)idxn[mt] * 256 + ct * 32);
#pragma unroll
        for (int ct = 0; ct < CT; ct++) {
            bf16x8 w0 = *(const bf16x8*)(wp + ct * 1024);
            bf16x8 w1 = *(const bf16x8*)(wp + ct * 1024 + 512);
#pragma unroll
            for (int mt = 0; mt < MT; mt++) {
                acc[mt][0] = mfma16(a[mt][ct], w0, acc[mt][0]);
                acc[mt][1] = mfma16(a[mt][ct], w1, acc[mt][1]);
            }
        }
        wp += CT * 1024;
#pragma unroll
        for (int mt = 0; mt < MT; mt++) {
#pragma unroll
            for (int ct = 0; ct < CT; ct++) a[mt][ct] = b[mt][ct];
            idxn[mt] = idx2[mt];
        }
    }

    float b0c = bb[l15], b1c = bb[16 + l15];
    float g0c = gg[l15], g1c = gg[16 + l15];
    float be0c = bee[l15], be1c = bee[16 + l15];

#pragma unroll
    for (int mt = 0; mt < MT; mt++) {
#pragma unroll
        for (int r = 0; r < 4; r++) {
            long row = base + mt * 16 + q * 4 + r;
            float v0 = acc[mt][0][r] + b0c;
            float v1 = acc[mt][1][r] + b1c;
            float s = v0 + v1, sq = v0 * v0 + v1 * v1;
#pragma unroll
            for (int m = 1; m < 16; m <<= 1) { s += __shfl_xor(s, m); sq += __shfl_xor(sq, m); }
            float mu = s * (1.f / 32), var = sq * (1.f / 32) - mu * mu, inv = rsqrtf(var + 1e-5f);
            float y0 = fmaxf((v0 - mu) * inv * g0c + be0c, 0.f);
            float y1 = fmaxf((v1 - mu) * inv * g1c + be1c, 0.f);
            unsigned short* cp = cat + row * 256 + out_off;
            cp[l15] = f2bf(y0);
            cp[16 + l15] = f2bf(y1);
        }
    }
}

// ---------------- final blk1: out = relu(LN(cat@W7 + b7)) ----------------
__global__ __launch_bounds__(256) void blk7_kernel(
    const unsigned short* __restrict__ cat, const unsigned short* __restrict__ Wp,
    const float* __restrict__ b, const float* __restrict__ g, const float* __restrict__ be,
    float* __restrict__ out) {
    int tid = threadIdx.x, lane = tid & 63, wv = tid >> 6;
    int l15 = lane & 15, q = lane >> 4;
    long base = ((long)blockIdx.x * 4 + wv) * 16;

    float4_ acc[4];
#pragma unroll
    for (int i = 0; i < 4; i++) acc[i] = (float4_){0.f, 0.f, 0.f, 0.f};

#pragma unroll
    for (int kt = 0; kt < 8; kt++) {
        bf16x8 a = *(const bf16x8*)(cat + (base + l15) * 256 + kt * 32 + q * 8);
        const unsigned short* wp = Wp + (size_t)kt * 4 * 512;
#pragma unroll
        for (int nt = 0; nt < 4; nt++) {
            bf16x8 w = *(const bf16x8*)(wp + nt * 512 + lane * 8);
            acc[nt] = mfma16(a, w, acc[nt]);
        }
    }

    float bc[4], gc[4], bec[4];
#pragma unroll
    for (int nt = 0; nt < 4; nt++) {
        int j = nt * 16 + l15;
        bc[nt] = b[j]; gc[nt] = g[j]; bec[nt] = be[j];
    }

#pragma unroll
    for (int r = 0; r < 4; r++) {
        long row = base + q * 4 + r;
        float v[4], s = 0.f, sq = 0.f;
#pragma unroll
        for (int nt = 0; nt < 4; nt++) { v[nt] = acc[nt][r] + bc[nt]; s += v[nt]; sq += v[nt] * v[nt]; }
#pragma unroll
        for (int m = 1; m < 16; m <<= 1) { s += __shfl_xor(s, m); sq += __shfl_xor(sq, m); }
        float mu = s * (1.f / 64), var = sq * (1.f / 64) - mu * mu, inv = rsqrtf(var + 1e-5f);
#pragma unroll
        for (int nt = 0; nt < 4; nt++) {
            float y = fmaxf((v[nt] - mu) * inv * gc[nt] + bec[nt], 0.f);
            out[row * 64 + nt * 16 + l15] = y;
        }
    }
}

extern "C" void kernel_launch(void* const* d_in, const int* in_sizes, int n_in,
                              void* d_out, int out_size, void* d_ws, size_t ws_size,
                              hipStream_t stream) {
    const int N = in_sizes[0] / 64;   // 262144

    const float* x   = (const float*)d_in[0];
    const int*   nbr = (const int*)d_in[1];
    const float* W1 = (const float*)d_in[2];
    const float* b1 = (const float*)d_in[3];
    const float* g1 = (const float*)d_in[4];
    const float* be1 = (const float*)d_in[5];
    const float* W2 = (const float*)d_in[6];
    const float* b2 = (const float*)d_in[7];
    const float* g2 = (const float*)d_in[8];
    const float* be2 = (const float*)d_in[9];
    const float* W3 = (const float*)d_in[10];
    const float* b3 = (const float*)d_in[11];
    const float* g3 = (const float*)d_in[12];
    const float* be3 = (const float*)d_in[13];
    const float* W4 = (const float*)d_in[14];
    const float* b4 = (const float*)d_in[15];
    const float* g4 = (const float*)d_in[16];
    const float* be4 = (const float*)d_in[17];
    const float* W5 = (const float*)d_in[18];
    const float* b5 = (const float*)d_in[19];
    const float* g5 = (const float*)d_in[20];
    const float* be5 = (const float*)d_in[21];
    const float* W6 = (const float*)d_in[22];
    const float* b6 = (const float*)d_in[23];
    const float* g6 = (const float*)d_in[24];
    const float* be6 = (const float*)d_in[25];
    const float* W7 = (const float*)d_in[26];
    const float* b7 = (const float*)d_in[27];
    const float* g7 = (const float*)d_in[28];
    const float* be7 = (const float*)d_in[29];

    unsigned short* ws   = (unsigned short*)d_ws;
    unsigned short* cat  = ws;                               // (N+1)*256 bf16
    unsigned short* Wp12 = cat + (size_t)(N + 1) * 256;      // 8192
    unsigned short* Wp3  = Wp12 + 8192;                      // 27*2*2*512 = 55296
    unsigned short* Wp4  = Wp3 + 55296;                      // 27*1*2*512 = 27648
    unsigned short* Wp5  = Wp4 + 27648;
    unsigned short* Wp6  = Wp5 + 27648;
    unsigned short* Wp7  = Wp6 + 27648;                      // 8*4*512 = 16384

    zero_row_kernel<<<1, 128, 0, stream>>>(cat, N);
    pack2_kernel<<<32, 256, 0, stream>>>(W1, W2, Wp12);
    packW_kernel<<<(55296 + 255) / 256, 256, 0, stream>>>(W3, Wp3, 64, 32, 55296);
    packW_kernel<<<(27648 + 255) / 256, 256, 0, stream>>>(W4, Wp4, 32, 32, 27648);
    packW_kernel<<<(27648 + 255) / 256, 256, 0, stream>>>(W5, Wp5, 32, 32, 27648);
    packW_kernel<<<(27648 + 255) / 256, 256, 0, stream>>>(W6, Wp6, 32, 32, 27648);
    packW_kernel<<<(16384 + 255) / 256, 256, 0, stream>>>(W7, Wp7, 256, 64, 16384);

    blk12_kernel<<<N / 64, 256, 0, stream>>>(x, cat, Wp12, b1, g1, be1, b2, g2, be2);
    conv_kernel<2, 2><<<N / 128, 256, 0, stream>>>(cat, nbr, Wp3, b3, g3, be3, 64, 128, N);
    conv_kernel<1, 4><<<N / 256, 256, 0, stream>>>(cat, nbr, Wp4, b4, g4, be4, 128, 160, N);
    conv_kernel<1, 4><<<N / 256, 256, 0, stream>>>(cat, nbr, Wp5, b5, g5, be5, 160, 192, N);
    conv_kernel<1, 4><<<N / 256, 256, 0, stream>>>(cat, nbr, Wp6, b6, g6, be6, 192, 224, N);
    blk7_kernel<<<N / 64, 256, 0, stream>>>(cat, Wp7, b7, g7, be7, (float*)d_out);
}

// Round 3
// 441.421 us; speedup vs baseline: 1.2352x; 1.1543x over previous
//
#include <hip/hip_runtime.h>

typedef __attribute__((ext_vector_type(4))) float  float4_;
typedef __attribute__((ext_vector_type(8))) short  short8;
typedef __attribute__((ext_vector_type(8))) __bf16 bf16x8;

__device__ inline unsigned short f2bf(float f) {
    unsigned u = __builtin_bit_cast(unsigned, f);
    u += 0x7FFFu + ((u >> 16) & 1u);          // round-to-nearest-even
    return (unsigned short)(u >> 16);
}

__device__ inline float4_ mfma16(bf16x8 a, bf16x8 b, float4_ c) {
    return __builtin_amdgcn_mfma_f32_16x16x32_bf16(a, b, c, 0, 0, 0);
}

// ---------------- one merged setup kernel ----------------
// packs all weights into B-fragment order + zeroes sentinel row cat[N].
// frag f = (k*ctn + ct)*ntn + nt ; elem = lane*8 + t
// value = W[k][ct*32 + (lane>>4)*8 + t][nt*16 + (lane&15)]
__device__ inline void packW_one(const float* __restrict__ src, unsigned short* __restrict__ dst,
                                 int cin, int cout, int e) {
    int f = e >> 9, i = e & 511, lane = i >> 3, t = i & 7;
    int ntn = cout >> 4, ctn = cin >> 5;
    int nt = f % ntn;
    int rest = f / ntn;
    int ct = rest % ctn;
    int k = rest / ctn;
    int c = ct * 32 + (lane >> 4) * 8 + t;
    int j = nt * 16 + (lane & 15);
    dst[e] = f2bf(src[(k * cin + c) * cout + j]);
}

__global__ void pack_all_kernel(
    const float* __restrict__ W1, const float* __restrict__ W2,
    const float* __restrict__ W3, const float* __restrict__ W4,
    const float* __restrict__ W5, const float* __restrict__ W6,
    const float* __restrict__ W7,
    unsigned short* cat, unsigned short* Wp12, unsigned short* Wp3,
    unsigned short* Wp4, unsigned short* Wp5, unsigned short* Wp6,
    unsigned short* Wp7, int N) {
    int e = blockIdx.x * 256 + threadIdx.x;
    if (e < 8192) {                                  // W1|W2 -> (64,128)
        int f = e >> 9, i = e & 511, lane = i >> 3, t = i & 7;
        int nt = f & 7, ct = f >> 3;
        int c = ct * 32 + (lane >> 4) * 8 + t;
        int j = nt * 16 + (lane & 15);
        float v = (j < 64) ? W1[c * 64 + j] : W2[c * 64 + (j - 64)];
        Wp12[e] = f2bf(v);
        return;
    }
    e -= 8192;
    if (e < 55296) { packW_one(W3, Wp3, 64, 32, e); return; }
    e -= 55296;
    if (e < 27648) { packW_one(W4, Wp4, 32, 32, e); return; }
    e -= 27648;
    if (e < 27648) { packW_one(W5, Wp5, 32, 32, e); return; }
    e -= 27648;
    if (e < 27648) { packW_one(W6, Wp6, 32, 32, e); return; }
    e -= 27648;
    if (e < 16384) { packW_one(W7, Wp7, 256, 64, e); return; }
    e -= 16384;
    if (e < 128) ((unsigned*)(cat + (size_t)N * 256))[e] = 0;   // sentinel row
}

// ---------------- blk1 dual: f1|f2 = relu(LN(x@W + b)) ----------------
__global__ __launch_bounds__(256) void blk12_kernel(
    const float* __restrict__ x, unsigned short* cat,
    const unsigned short* __restrict__ Wp,
    const float* __restrict__ b1, const float* __restrict__ g1, const float* __restrict__ be1,
    const float* __restrict__ b2, const float* __restrict__ g2, const float* __restrict__ be2) {
    int tid = threadIdx.x, lane = tid & 63, wv = tid >> 6;
    int l15 = lane & 15, q = lane >> 4;
    long base = ((long)blockIdx.x * 4 + wv) * 16;

    float4_ acc[8];
#pragma unroll
    for (int i = 0; i < 8; i++) acc[i] = (float4_){0.f, 0.f, 0.f, 0.f};

#pragma unroll
    for (int kt = 0; kt < 2; kt++) {
        const float* xp = x + (base + l15) * 64 + kt * 32 + q * 8;
        float4_ f0 = *(const float4_*)xp;
        float4_ f1 = *(const float4_*)(xp + 4);
        short8 as;
        as[0] = (short)f2bf(f0[0]); as[1] = (short)f2bf(f0[1]);
        as[2] = (short)f2bf(f0[2]); as[3] = (short)f2bf(f0[3]);
        as[4] = (short)f2bf(f1[0]); as[5] = (short)f2bf(f1[1]);
        as[6] = (short)f2bf(f1[2]); as[7] = (short)f2bf(f1[3]);
        bf16x8 a = __builtin_bit_cast(bf16x8, as);
        const unsigned short* wp = Wp + (size_t)kt * 8 * 512;
#pragma unroll
        for (int nt = 0; nt < 8; nt++) {
            bf16x8 w = *(const bf16x8*)(wp + nt * 512 + lane * 8);
            acc[nt] = mfma16(a, w, acc[nt]);
        }
    }

    float bc[8], gc[8], bec[8];
#pragma unroll
    for (int nt = 0; nt < 8; nt++) {
        int j = nt * 16 + l15;
        if (j < 64) { bc[nt] = b1[j]; gc[nt] = g1[j]; bec[nt] = be1[j]; }
        else        { bc[nt] = b2[j - 64]; gc[nt] = g2[j - 64]; bec[nt] = be2[j - 64]; }
    }

#pragma unroll
    for (int r = 0; r < 4; r++) {
        long row = base + q * 4 + r;
        float v[8], s0 = 0.f, s1 = 0.f, q0 = 0.f, q1 = 0.f;
#pragma unroll
        for (int nt = 0; nt < 4; nt++) { v[nt] = acc[nt][r] + bc[nt]; s0 += v[nt]; q0 += v[nt] * v[nt]; }
#pragma unroll
        for (int nt = 4; nt < 8; nt++) { v[nt] = acc[nt][r] + bc[nt]; s1 += v[nt]; q1 += v[nt] * v[nt]; }
#pragma unroll
        for (int m = 1; m < 16; m <<= 1) {
            s0 += __shfl_xor(s0, m); q0 += __shfl_xor(q0, m);
            s1 += __shfl_xor(s1, m); q1 += __shfl_xor(q1, m);
        }
        float mu0 = s0 * (1.f / 64), var0 = q0 * (1.f / 64) - mu0 * mu0, inv0 = rsqrtf(var0 + 1e-5f);
        float mu1 = s1 * (1.f / 64), var1 = q1 * (1.f / 64) - mu1 * mu1, inv1 = rsqrtf(var1 + 1e-5f);
        unsigned short* cp = cat + row * 256;
#pragma unroll
        for (int nt = 0; nt < 4; nt++) {
            float y = fmaxf((v[nt] - mu0) * inv0 * gc[nt] + bec[nt], 0.f);
            cp[nt * 16 + l15] = f2bf(y);
        }
#pragma unroll
        for (int nt = 4; nt < 8; nt++) {
            float y = fmaxf((v[nt] - mu1) * inv1 * gc[nt] + bec[nt], 0.f);
            cp[nt * 16 + l15] = f2bf(y);
        }
    }
}

// ---------------- submanifold conv blk3 ----------------
// Deep register pipeline, need-ordered vmem issue so in-order vmcnt waits
// never drain young loads:
//   per iter k: issue W(k+2) -> gather(k+D) -> rawidx(k+D+2), then MFMA(k).
// Rings (full 27-unroll folds all mod indices):
//   f[D+1]  gather frags   (lead D iters)
//   wr[3]   weight frags   (lead 2 iters)
//   rawi[3] raw nbr idx    (lead 2 iters ahead of gather issue)
// Invalid neighbor -> sentinel zero row cat[N] (cndmask).
// MT=2 (32 rows/wave), 2 n-tiles (32 out ch), CT = cin/32.
template <int CT, int D>
__global__ __launch_bounds__(256) void conv_kernel(
    unsigned short* cat, const int* __restrict__ nbr,
    const unsigned short* __restrict__ Wp,
    const float* __restrict__ bb, const float* __restrict__ gg, const float* __restrict__ bee,
    int in_off, int out_off, int N) {
    const int MT = 2;
    int tid = threadIdx.x, lane = tid & 63, wv = tid >> 6;
    int l15 = lane & 15, q = lane >> 4;
    long base = ((long)blockIdx.x * 4 + wv) * 32;

    float4_ acc[MT][2];
#pragma unroll
    for (int mt = 0; mt < MT; mt++) {
        acc[mt][0] = (float4_){0.f, 0.f, 0.f, 0.f};
        acc[mt][1] = (float4_){0.f, 0.f, 0.f, 0.f};
    }

    const unsigned short* catp = cat + in_off + q * 8;
    const unsigned short* wl = Wp + lane * 8;
    const int* nbp[MT];
#pragma unroll
    for (int mt = 0; mt < MT; mt++) nbp[mt] = nbr + (base + mt * 16 + l15) * 27;

    bf16x8 f[D + 1][MT][CT];
    bf16x8 wr[3][CT][2];
    int rawi[3][MT];

    // ---- prologue ----
    int raw0[D + 2][MT];
#pragma unroll
    for (int j = 0; j < D + 2; j++)
#pragma unroll
        for (int mt = 0; mt < MT; mt++) raw0[j][mt] = nbp[mt][j];

#pragma unroll
    for (int kk = 0; kk < 2; kk++)
#pragma unroll
        for (int ct = 0; ct < CT; ct++)
#pragma unroll
            for (int nt = 0; nt < 2; nt++)
                wr[kk][ct][nt] = *(const bf16x8*)(wl + ((size_t)((kk * CT + ct) * 2 + nt)) * 512);

#pragma unroll
    for (int j = 0; j < D; j++)
#pragma unroll
        for (int mt = 0; mt < MT; mt++) {
            int v = raw0[j][mt];
            size_t s = (size_t)(v < 0 ? N : v);
#pragma unroll
            for (int ct = 0; ct < CT; ct++)
                f[j][mt][ct] = *(const bf16x8*)(catp + s * 256 + ct * 32);
        }
#pragma unroll
    for (int mt = 0; mt < MT; mt++) {
        rawi[D % 3][mt] = raw0[D][mt];
        rawi[(D + 1) % 3][mt] = raw0[D + 1][mt];
    }

    // ---- main loop ----
#pragma unroll
    for (int k = 0; k < 27; k++) {
        if (k + 2 < 27) {                       // weights for k+2
#pragma unroll
            for (int ct = 0; ct < CT; ct++)
#pragma unroll
                for (int nt = 0; nt < 2; nt++)
                    wr[(k + 2) % 3][ct][nt] =
                        *(const bf16x8*)(wl + ((size_t)(((k + 2) * CT + ct) * 2 + nt)) * 512);
        }
        if (k + D < 27) {                       // gathers for k+D
#pragma unroll
            for (int mt = 0; mt < MT; mt++) {
                int v = rawi[(k + D) % 3][mt];
                size_t s = (size_t)(v < 0 ? N : v);
#pragma unroll
                for (int ct = 0; ct < CT; ct++)
                    f[(k + D) % (D + 1)][mt][ct] = *(const bf16x8*)(catp + s * 256 + ct * 32);
            }
        }
        if (k + D + 2 < 27) {                   // raw idx for k+D+2
#pragma unroll
            for (int mt = 0; mt < MT; mt++) rawi[(k + D + 2) % 3][mt] = nbp[mt][k + D + 2];
        }
#pragma unroll
        for (int ct = 0; ct < CT; ct++) {
            bf16x8 w0 = wr[k % 3][ct][0];
            bf16x8 w1 = wr[k % 3][ct][1];
#pragma unroll
            for (int mt = 0; mt < MT; mt++) {
                acc[mt][0] = mfma16(f[k % (D + 1)][mt][ct], w0, acc[mt][0]);
                acc[mt][1] = mfma16(f[k % (D + 1)][mt][ct], w1, acc[mt][1]);
            }
        }
    }

    // ---- epilogue: bias + LN + relu + store ----
    float b0c = bb[l15], b1c = bb[16 + l15];
    float g0c = gg[l15], g1c = gg[16 + l15];
    float be0c = bee[l15], be1c = bee[16 + l15];

#pragma unroll
    for (int mt = 0; mt < MT; mt++) {
#pragma unroll
        for (int r = 0; r < 4; r++) {
            long row = base + mt * 16 + q * 4 + r;
            float v0 = acc[mt][0][r] + b0c;
            float v1 = acc[mt][1][r] + b1c;
            float s = v0 + v1, sq = v0 * v0 + v1 * v1;
#pragma unroll
            for (int m = 1; m < 16; m <<= 1) { s += __shfl_xor(s, m); sq += __shfl_xor(sq, m); }
            float mu = s * (1.f / 32), var = sq * (1.f / 32) - mu * mu, inv = rsqrtf(var + 1e-5f);
            float y0 = fmaxf((v0 - mu) * inv * g0c + be0c, 0.f);
            float y1 = fmaxf((v1 - mu) * inv * g1c + be1c, 0.f);
            unsigned short* cp = cat + row * 256 + out_off;
            cp[l15] = f2bf(y0);
            cp[16 + l15] = f2bf(y1);
        }
    }
}

// ---------------- final blk1: out = relu(LN(cat@W7 + b7)) ----------------
__global__ __launch_bounds__(256) void blk7_kernel(
    const unsigned short* __restrict__ cat, const unsigned short* __restrict__ Wp,
    const float* __restrict__ b, const float* __restrict__ g, const float* __restrict__ be,
    float* __restrict__ out) {
    int tid = threadIdx.x, lane = tid & 63, wv = tid >> 6;
    int l15 = lane & 15, q = lane >> 4;
    long base = ((long)blockIdx.x * 4 + wv) * 16;

    float4_ acc[4];
#pragma unroll
    for (int i = 0; i < 4; i++) acc[i] = (float4_){0.f, 0.f, 0.f, 0.f};

#pragma unroll
    for (int kt = 0; kt < 8; kt++) {
        bf16x8 a = *(const bf16x8*)(cat + (base + l15) * 256 + kt * 32 + q * 8);
        const unsigned short* wp = Wp + (size_t)kt * 4 * 512;
#pragma unroll
        for (int nt = 0; nt < 4; nt++) {
            bf16x8 w = *(const bf16x8*)(wp + nt * 512 + lane * 8);
            acc[nt] = mfma16(a, w, acc[nt]);
        }
    }

    float bc[4], gc[4], bec[4];
#pragma unroll
    for (int nt = 0; nt < 4; nt++) {
        int j = nt * 16 + l15;
        bc[nt] = b[j]; gc[nt] = g[j]; bec[nt] = be[j];
    }

#pragma unroll
    for (int r = 0; r < 4; r++) {
        long row = base + q * 4 + r;
        float v[4], s = 0.f, sq = 0.f;
#pragma unroll
        for (int nt = 0; nt < 4; nt++) { v[nt] = acc[nt][r] + bc[nt]; s += v[nt]; sq += v[nt] * v[nt]; }
#pragma unroll
        for (int m = 1; m < 16; m <<= 1) { s += __shfl_xor(s, m); sq += __shfl_xor(sq, m); }
        float mu = s * (1.f / 64), var = sq * (1.f / 64) - mu * mu, inv = rsqrtf(var + 1e-5f);
#pragma unroll
        for (int nt = 0; nt < 4; nt++) {
            float y = fmaxf((v[nt] - mu) * inv * gc[nt] + bec[nt], 0.f);
            out[row * 64 + nt * 16 + l15] = y;
        }
    }
}

extern "C" void kernel_launch(void* const* d_in, const int* in_sizes, int n_in,
                              void* d_out, int out_size, void* d_ws, size_t ws_size,
                              hipStream_t stream) {
    const int N = in_sizes[0] / 64;   // 262144

    const float* x   = (const float*)d_in[0];
    const int*   nbr = (const int*)d_in[1];
    const float* W1 = (const float*)d_in[2];
    const float* b1 = (const float*)d_in[3];
    const float* g1 = (const float*)d_in[4];
    const float* be1 = (const float*)d_in[5];
    const float* W2 = (const float*)d_in[6];
    const float* b2 = (const float*)d_in[7];
    const float* g2 = (const float*)d_in[8];
    const float* be2 = (const float*)d_in[9];
    const float* W3 = (const float*)d_in[10];
    const float* b3 = (const float*)d_in[11];
    const float* g3 = (const float*)d_in[12];
    const float* be3 = (const float*)d_in[13];
    const float* W4 = (const float*)d_in[14];
    const float* b4 = (const float*)d_in[15];
    const float* g4 = (const float*)d_in[16];
    const float* be4 = (const float*)d_in[17];
    const float* W5 = (const float*)d_in[18];
    const float* b5 = (const float*)d_in[19];
    const float* g5 = (const float*)d_in[20];
    const float* be5 = (const float*)d_in[21];
    const float* W6 = (const float*)d_in[22];
    const float* b6 = (const float*)d_in[23];
    const float* g6 = (const float*)d_in[24];
    const float* be6 = (const float*)d_in[25];
    const float* W7 = (const float*)d_in[26];
    const float* b7 = (const float*)d_in[27];
    const float* g7 = (const float*)d_in[28];
    const float* be7 = (const float*)d_in[29];

    unsigned short* ws   = (unsigned short*)d_ws;
    unsigned short* cat  = ws;                               // (N+1)*256 bf16
    unsigned short* Wp12 = cat + (size_t)(N + 1) * 256;      // 8192
    unsigned short* Wp3  = Wp12 + 8192;                      // 27*2*2*512 = 55296
    unsigned short* Wp4  = Wp3 + 55296;                      // 27*1*2*512 = 27648
    unsigned short* Wp5  = Wp4 + 27648;
    unsigned short* Wp6  = Wp5 + 27648;
    unsigned short* Wp7  = Wp6 + 27648;                      // 8*4*512 = 16384

    pack_all_kernel<<<637, 256, 0, stream>>>(W1, W2, W3, W4, W5, W6, W7,
                                             cat, Wp12, Wp3, Wp4, Wp5, Wp6, Wp7, N);

    blk12_kernel<<<N / 64, 256, 0, stream>>>(x, cat, Wp12, b1, g1, be1, b2, g2, be2);
    conv_kernel<2, 3><<<N / 128, 256, 0, stream>>>(cat, nbr, Wp3, b3, g3, be3, 64, 128, N);
    conv_kernel<1, 4><<<N / 128, 256, 0, stream>>>(cat, nbr, Wp4, b4, g4, be4, 128, 160, N);
    conv_kernel<1, 4><<<N / 128, 256, 0, stream>>>(cat, nbr, Wp5, b5, g5, be5, 160, 192, N);
    conv_kernel<1, 4><<<N / 128, 256, 0, stream>>>(cat, nbr, Wp6, b6, g6, be6, 192, 224, N);
    blk7_kernel<<<N / 64, 256, 0, stream>>>(cat, Wp7, b7, g7, be7, (float*)d_out);
}